// Round 13
// baseline (903.249 us; speedup 1.0000x reference)
//
#include <hip/hip_runtime.h>

#define N_NODES 10000
#define N_CFG   16
#define N_EDGES 40000
#define UW      512               // U row: [agg 256 | x 256] (x updated in-place)

typedef __attribute__((ext_vector_type(8))) short bf16x8;
typedef __attribute__((ext_vector_type(4))) float floatx4;

__device__ __forceinline__ unsigned short f2bf(float f) {
    union { float f; unsigned int u; } v; v.f = f;
    unsigned int r = (v.u + 0x7fffu + ((v.u >> 16) & 1u)) >> 16;  // RNE
    return (unsigned short)r;
}
__device__ __forceinline__ float bf2f(unsigned short h) {
    union { unsigned int u; float f; } v; v.u = ((unsigned int)h) << 16;
    return v.f;
}
// acc[0..7] += 8 bf16 packed in uint4
__device__ __forceinline__ void add8(float* acc, uint4 v) {
    acc[0] += bf2f(v.x & 0xffff); acc[1] += bf2f(v.x >> 16);
    acc[2] += bf2f(v.y & 0xffff); acc[3] += bf2f(v.y >> 16);
    acc[4] += bf2f(v.z & 0xffff); acc[5] += bf2f(v.z >> 16);
    acc[6] += bf2f(v.w & 0xffff); acc[7] += bf2f(v.w >> 16);
}

// async global->LDS, 16B/lane; LDS dest MUST be wave-uniform + lane*16
__device__ __forceinline__ void gl_lds16(const unsigned short* g, unsigned short* l) {
    __builtin_amdgcn_global_load_lds(
        (const __attribute__((address_space(1))) unsigned int*)g,
        (__attribute__((address_space(3))) unsigned int*)l, 16, 0, 0);
}

// ---------------------------------------------------------------------------
// Feature build
// ---------------------------------------------------------------------------

__global__ __launch_bounds__(256) void k_table(const float* __restrict__ emb_layout,
                                               const float* __restrict__ lin_w,
                                               unsigned short* __restrict__ T) {
    int b = blockIdx.x;  // 0..143
    int j = b >> 3, v = b & 7;
    int d = threadIdx.x;
    float s = 0.f;
#pragma unroll
    for (int t = 0; t < 4; ++t)
        s = fmaf(emb_layout[v * 4 + t], lin_w[(140 + 4 * j + t) * 256 + d], s);
    T[b * 256 + d] = f2bf(s);
}

// 20 nodes per block: lin_w read once per block (k-outer loop)
__global__ __launch_bounds__(256) void k_base(const float* __restrict__ x_feat,
                                              const int* __restrict__ x_op,
                                              const float* __restrict__ emb_op,
                                              const float* __restrict__ lin_w,
                                              const float* __restrict__ lin_b,
                                              unsigned short* __restrict__ base) {
    __shared__ float xf[20][144];
    const int tid = threadIdx.x;
    const int n0 = blockIdx.x * 20;
    for (int j = tid; j < 20 * 140; j += 256)
        xf[j / 140][j % 140] = x_feat[(n0 + j / 140) * 140 + (j % 140)];
    if (tid < 80) {
        int i = tid >> 2, t = tid & 3;
        xf[i][140 + t] = emb_op[x_op[n0 + i] * 4 + t];
    }
    __syncthreads();
    const int d = tid;
    float acc[20];
#pragma unroll
    for (int i = 0; i < 20; ++i) acc[i] = 0.f;
    for (int k = 0; k < 140; ++k) {
        float w = lin_w[k * 256 + d];
#pragma unroll
        for (int i = 0; i < 20; ++i) acc[i] = fmaf(xf[i][k], w, acc[i]);
    }
#pragma unroll
    for (int t = 0; t < 4; ++t) {
        float w = lin_w[(212 + t) * 256 + d];
#pragma unroll
        for (int i = 0; i < 20; ++i) acc[i] = fmaf(xf[i][140 + t], w, acc[i]);
    }
    float bb = lin_b[d];
#pragma unroll
    for (int i = 0; i < 20; ++i)
        base[(n0 + i) * 256 + d] = f2bf(acc[i] + bb);
}

// x0 -> U x cols. Vectorized: 8 nodes/block, 32 threads/node, 8 cols/thread.
template <int CH>
__global__ __launch_bounds__(256) void k_x0(const unsigned short* __restrict__ base,
                                            const unsigned short* __restrict__ T,
                                            const int* __restrict__ cfg,
                                            unsigned short* __restrict__ U,
                                            int cc) {
    __shared__ int idx[8][18];
    const int tid = threadIdx.x;
    const int n0 = blockIdx.x * 8;
    const int cy = blockIdx.y;
    const int cg = cc * CH + cy;
    if (tid < 144) {
        int nl = tid / 18, j = tid % 18;
        idx[nl][j] = cfg[((size_t)cg * N_NODES + n0 + nl) * 18 + j];
    }
    __syncthreads();
    const int nl = tid >> 5;
    const int colg = (tid & 31) * 8;
    const int n = n0 + nl;
    float acc[8];
    uint4 bv = *(const uint4*)(base + n * 256 + colg);
    acc[0] = bf2f(bv.x & 0xffff); acc[1] = bf2f(bv.x >> 16);
    acc[2] = bf2f(bv.y & 0xffff); acc[3] = bf2f(bv.y >> 16);
    acc[4] = bf2f(bv.z & 0xffff); acc[5] = bf2f(bv.z >> 16);
    acc[6] = bf2f(bv.w & 0xffff); acc[7] = bf2f(bv.w >> 16);
#pragma unroll
    for (int j = 0; j < 18; ++j) {
        uint4 tv = *(const uint4*)(T + (j * 8 + idx[nl][j]) * 256 + colg);
        add8(acc, tv);
    }
    uint4 o;
    o.x = (unsigned int)f2bf(acc[0]) | ((unsigned int)f2bf(acc[1]) << 16);
    o.y = (unsigned int)f2bf(acc[2]) | ((unsigned int)f2bf(acc[3]) << 16);
    o.z = (unsigned int)f2bf(acc[4]) | ((unsigned int)f2bf(acc[5]) << 16);
    o.w = (unsigned int)f2bf(acc[6]) | ((unsigned int)f2bf(acc[7]) << 16);
    *(uint4*)(U + ((size_t)cy * N_NODES + n) * UW + 256 + colg) = o;
}

// ---------------------------------------------------------------------------
// CSR build
// ---------------------------------------------------------------------------

__global__ void k_deg(const int* __restrict__ ei, int* __restrict__ deg) {
    int e = blockIdx.x * 256 + threadIdx.x;
    if (e < N_EDGES) atomicAdd(&deg[ei[N_EDGES + e]], 1);
}

// prefix-scan over deg -> coff, plus invd = 1/max(deg,1) in the same pass
__global__ __launch_bounds__(256) void k_scan(const int* __restrict__ deg,
                                              int* __restrict__ coff,
                                              float* __restrict__ invd) {
    __shared__ int part[257];
    int t = threadIdx.x;
    const int CHk = 40;
    int start = t * CHk;
    int s = 0;
    for (int i = 0; i < CHk; ++i) {
        int idx = start + i;
        if (idx < N_NODES) s += deg[idx];
    }
    part[t + 1] = s;
    if (t == 0) part[0] = 0;
    __syncthreads();
    if (t == 0)
        for (int i = 1; i <= 256; ++i) part[i] += part[i - 1];
    __syncthreads();
    int run = part[t];
    for (int i = 0; i < CHk; ++i) {
        int idx = start + i;
        if (idx < N_NODES) {
            int d = deg[idx];
            coff[idx] = run; run += d;
            invd[idx] = 1.0f / fmaxf((float)d, 1.0f);
        }
    }
    if (t == 0) coff[N_NODES] = part[256];
}

__global__ void k_fill(const int* __restrict__ ei, const int* __restrict__ coff,
                       int* __restrict__ cur, int* __restrict__ csrc) {
    int e = blockIdx.x * 256 + threadIdx.x;
    if (e < N_EDGES) {
        int d = ei[N_EDGES + e];
        int s = ei[e];
        int pos = atomicAdd(&cur[d], 1);
        csrc[coff[d] + pos] = s;
    }
}

// WT[i][n][k]: k in [0,512) = bf16_hi(Wfused[k][n]); k in [512,1024) = bf16_lo
__global__ void k_wsplit(const float* __restrict__ wl, const float* __restrict__ wr,
                         unsigned short* __restrict__ WT) {
    int t = blockIdx.x * 256 + threadIdx.x;  // < 524288
    int i = t >> 17;
    int r = (t >> 8) & 511;
    int nn = t & 255;
    float w = (r < 256) ? wl[i * 65536 + r * 256 + nn]
                        : wr[i * 65536 + (r - 256) * 256 + nn];
    unsigned short hi = f2bf(w);
    unsigned short lo = f2bf(w - bf2f(hi));
    size_t b = (size_t)i * 262144 + (size_t)nn * 1024;
    WT[b + r] = hi;
    WT[b + 512 + r] = lo;
}

// ---------------------------------------------------------------------------
// Aggregation: one wave per (node, config) — grid.y = CH. Max TLP for the
// latency-bound gather (mean degree 4 -> ~2 iterations per half-wave).
// 16B loads, half-wave edge parity, shfl_xor(32) merge.
// ---------------------------------------------------------------------------

__global__ __launch_bounds__(256) void k_agg(unsigned short* __restrict__ U,
                                             const int* __restrict__ coff,
                                             const int* __restrict__ csrc,
                                             const float* __restrict__ invd) {
    const int wave = threadIdx.x >> 6, lane = threadIdx.x & 63;
    const int n = blockIdx.x * 4 + wave;
    const size_t cbase = (size_t)blockIdx.y * N_NODES;
    const int e0 = coff[n], e1 = coff[n + 1];
    const int h = lane >> 5;          // edge parity
    const int cg = (lane & 31) * 8;   // col start
    float acc[8];
#pragma unroll
    for (int j = 0; j < 8; ++j) acc[j] = 0.f;
    for (int e = e0 + h; e < e1; e += 2) {
        int s = csrc[e];
        uint4 v = *(const uint4*)(U + (cbase + s) * UW + 256 + cg);
        add8(acc, v);
    }
#pragma unroll
    for (int j = 0; j < 8; ++j)
        acc[j] += __shfl_xor(acc[j], 32, 64);
    if (h == 0) {
        float iv = invd[n];
        uint4 o;
        o.x = (unsigned int)f2bf(acc[0] * iv) | ((unsigned int)f2bf(acc[1] * iv) << 16);
        o.y = (unsigned int)f2bf(acc[2] * iv) | ((unsigned int)f2bf(acc[3] * iv) << 16);
        o.z = (unsigned int)f2bf(acc[4] * iv) | ((unsigned int)f2bf(acc[5] * iv) << 16);
        o.w = (unsigned int)f2bf(acc[6] * iv) | ((unsigned int)f2bf(acc[7] * iv) << 16);
        *(uint4*)(U + (cbase + n) * UW + cg) = o;
    }
}

// ---------------------------------------------------------------------------
// MFMA GEMM (r10/r12 config — measured best): x = relu([agg|x]@(W_hi+W_lo)+b),
// in place. BM=128, BN=256 via 512 threads (8 waves, 64x64 quadrants;
// acc=64 VGPRs). global_load_lds staging; 40 KB LDS; XOR swizzle (0 conflicts).
// At the m97-structure MfmaUtil plateau (~38%) — do not touch.
// ---------------------------------------------------------------------------

__global__ __launch_bounds__(512) void k_gemm(unsigned short* __restrict__ U,
                                              const unsigned short* __restrict__ WTl,
                                              const float* __restrict__ bias) {
    __shared__ unsigned short Asm[128 * 32];   // 8 KB
    __shared__ unsigned short Bh[256 * 32];    // 16 KB
    __shared__ unsigned short Bl[256 * 32];    // 16 KB
    const int tid = threadIdx.x;
    const int lane = tid & 63;
    const int wave = tid >> 6;                 // 0..7
    const int wm = wave >> 2;                  // row half (0/1)
    const int wn = wave & 3;                   // n-slice (64 wide)
    const size_t r0 = (size_t)blockIdx.x * 128;

    const int srow = tid >> 2;                     // staged row 0..127
    const int gc = (tid & 3) ^ ((srow >> 1) & 3);  // fetched k-granule (swizzle)

    const int colg = lane & 15, kg = lane >> 4, quad = lane >> 4;
    int aoff[4], boff[4];
#pragma unroll
    for (int t = 0; t < 4; ++t) {
        int ar = wm * 64 + t * 16 + colg;
        aoff[t] = ar * 32 + ((kg ^ ((ar >> 1) & 3)) << 3);
        int br = wn * 64 + t * 16 + colg;
        boff[t] = br * 32 + ((kg ^ ((br >> 1) & 3)) << 3);
    }

    floatx4 acc[4][4];
#pragma unroll
    for (int i = 0; i < 4; ++i)
#pragma unroll
        for (int j = 0; j < 4; ++j) acc[i][j] = (floatx4){0.f, 0.f, 0.f, 0.f};

    const unsigned short* Arow  = U + (r0 + srow) * UW + gc * 8;
    const unsigned short* Wrow0 = WTl + (size_t)srow * 1024 + gc * 8;          // n 0..127
    const unsigned short* Wrow1 = WTl + (size_t)(128 + srow) * 1024 + gc * 8;  // n 128..255

    for (int kt = 0; kt < 512; kt += 32) {
        gl_lds16(Arow + kt, Asm + tid * 8);
        gl_lds16(Wrow0 + kt,       Bh + tid * 8);
        gl_lds16(Wrow1 + kt,       Bh + 4096 + tid * 8);
        gl_lds16(Wrow0 + 512 + kt, Bl + tid * 8);
        gl_lds16(Wrow1 + 512 + kt, Bl + 4096 + tid * 8);
        __syncthreads();  // drains vmcnt -> staged data visible

        bf16x8 a[4], bh[4], bl[4];
#pragma unroll
        for (int t = 0; t < 4; ++t) a[t] = *(const bf16x8*)(Asm + aoff[t]);
#pragma unroll
        for (int t = 0; t < 4; ++t) {
            bh[t] = *(const bf16x8*)(Bh + boff[t]);
            bl[t] = *(const bf16x8*)(Bl + boff[t]);
        }
#pragma unroll
        for (int ti = 0; ti < 4; ++ti)
#pragma unroll
            for (int tj = 0; tj < 4; ++tj)
                acc[ti][tj] = __builtin_amdgcn_mfma_f32_16x16x32_bf16(
                    a[ti], bh[tj], acc[ti][tj], 0, 0, 0);
#pragma unroll
        for (int ti = 0; ti < 4; ++ti)
#pragma unroll
            for (int tj = 0; tj < 4; ++tj)
                acc[ti][tj] = __builtin_amdgcn_mfma_f32_16x16x32_bf16(
                    a[ti], bl[tj], acc[ti][tj], 0, 0, 0);
        __syncthreads();  // all waves done with LDS before restage
    }

#pragma unroll
    for (int tj = 0; tj < 4; ++tj) {
        int nn = wn * 64 + tj * 16 + colg;
        float bv = bias[nn];
#pragma unroll
        for (int ti = 0; ti < 4; ++ti) {
#pragma unroll
            for (int r = 0; r < 4; ++r) {
                size_t mm = r0 + (size_t)(wm * 64 + ti * 16 + quad * 4 + r);
                float y = acc[ti][tj][r] + bv;
                U[mm * UW + 256 + nn] = f2bf(fmaxf(y, 0.f));
            }
        }
    }
}

// ---------------------------------------------------------------------------
// Pool (vectorized: 8 row-groups x 32 lanes, uint4 reads, LDS reduce) + head
// ---------------------------------------------------------------------------

template <int CH>
__global__ __launch_bounds__(256) void k_pool(const unsigned short* __restrict__ U,
                                              float* __restrict__ g, int cc) {
    __shared__ float red[8][256];
    const int tid = threadIdx.x;
    const int grp = tid >> 5;          // row group 0..7
    const int cg = (tid & 31) * 8;     // col start
    const int cy = blockIdx.y;
    const size_t row0 = (size_t)cy * N_NODES + blockIdx.x * 250;
    float acc[8];
#pragma unroll
    for (int j = 0; j < 8; ++j) acc[j] = 0.f;
    for (int i = grp; i < 250; i += 8) {
        uint4 v = *(const uint4*)(U + (row0 + i) * UW + 256 + cg);
        add8(acc, v);
    }
#pragma unroll
    for (int j = 0; j < 8; ++j) red[grp][cg + j] = acc[j];
    __syncthreads();
    float s = 0.f;
#pragma unroll
    for (int k = 0; k < 8; ++k) s += red[k][tid];
    atomicAdd(&g[(cc * CH + cy) * 256 + tid], s);
}

__global__ __launch_bounds__(256) void k_head(const float* __restrict__ g,
                                              const float* __restrict__ w1,
                                              const float* __restrict__ b1,
                                              const float* __restrict__ w2,
                                              const float* __restrict__ b2,
                                              const float* __restrict__ w3,
                                              const float* __restrict__ b3,
                                              float* __restrict__ out) {
    __shared__ float ha[256];
    __shared__ float hb[256];
    __shared__ float red[4];
    int c = blockIdx.x;
    int d = threadIdx.x;
    ha[d] = g[c * 256 + d] / 10000.0f;
    __syncthreads();
    float s = b1[d];
#pragma unroll 4
    for (int k = 0; k < 256; ++k)
        s = fmaf(ha[k], w1[k * 256 + d], s);
    hb[d] = fmaxf(s, 0.f);
    __syncthreads();
    s = b2[d];
#pragma unroll 4
    for (int k = 0; k < 256; ++k)
        s = fmaf(hb[k], w2[k * 256 + d], s);
    ha[d] = fmaxf(s, 0.f);
    __syncthreads();
    float p = ha[d] * w3[d];
#pragma unroll
    for (int off = 32; off > 0; off >>= 1)
        p += __shfl_down(p, off, 64);
    if ((d & 63) == 0) red[d >> 6] = p;
    __syncthreads();
    if (d == 0)
        out[c] = red[0] + red[1] + red[2] + red[3] + b3[0];
}

__global__ void k_wsfail(float* __restrict__ out, float v) {
    out[threadIdx.x] = v;
}

// ---------------------------------------------------------------------------

extern "C" void kernel_launch(void* const* d_in, const int* in_sizes, int n_in,
                              void* d_out, int out_size, void* d_ws, size_t ws_size,
                              hipStream_t stream) {
    const int*   x_node_cfg = (const int*)  d_in[0];
    const float* x_feat     = (const float*)d_in[1];
    const int*   x_op       = (const int*)  d_in[2];
    const int*   edge_index = (const int*)  d_in[3];
    const float* emb_op     = (const float*)d_in[4];
    const float* emb_layout = (const float*)d_in[5];
    const float* lin_w      = (const float*)d_in[6];
    const float* lin_b      = (const float*)d_in[7];
    const float* conv_wl    = (const float*)d_in[8];
    const float* conv_bl    = (const float*)d_in[9];
    const float* conv_wr    = (const float*)d_in[10];
    const float* w1         = (const float*)d_in[11];
    const float* b1         = (const float*)d_in[12];
    const float* w2         = (const float*)d_in[13];
    const float* b2         = (const float*)d_in[14];
    const float* w3         = (const float*)d_in[15];
    const float* b3         = (const float*)d_in[16];
    float* out = (float*)d_out;

    // rest-of-workspace = 7,627,268 B; U = CH*10000*512*2 B
    const size_t NEED8  = (size_t)8  * N_NODES * UW * 2 + 7627268;  //  89.5 MB
    const size_t NEED16 = (size_t)16 * N_NODES * UW * 2 + 7627268;  // 171.5 MB
    const int CH = (ws_size >= NEED16) ? 16 : 8;

    unsigned short* U    = (unsigned short*)d_ws;          // [CH*10000][512]
    unsigned short* base = U + (size_t)CH * N_NODES * UW;  // [10000][256]
    unsigned short* T    = base + 2560000;                 // [18][8][256]
    unsigned short* WT   = T + 36864;                      // [4][256][1024]
    float* invd = (float*)(WT + 1048576);                  // [10000]
    float* g    = invd + 10000;                            // [16][256] pad 4096
    int* deg  = (int*)(g + 4096);                          // [10000]
    int* coff = deg + 10000;                               // [10001]
    int* cur  = coff + 10001;                              // [10000]
    int* csrc = cur + 10000;                               // [40000]

    if (ws_size < NEED8) {
        k_wsfail<<<1, 16, 0, stream>>>(out, (float)ws_size * 1e-9f);
        return;
    }

    hipMemsetAsync(deg, 0, N_NODES * sizeof(int), stream);
    hipMemsetAsync(cur, 0, N_NODES * sizeof(int), stream);
    hipMemsetAsync(g, 0, 4096 * sizeof(float), stream);

    k_table<<<144, 256, 0, stream>>>(emb_layout, lin_w, T);
    k_base<<<500, 256, 0, stream>>>(x_feat, x_op, emb_op, lin_w, lin_b, base);
    k_deg<<<(N_EDGES + 255) / 256, 256, 0, stream>>>(edge_index, deg);
    k_scan<<<1, 256, 0, stream>>>(deg, coff, invd);
    k_fill<<<(N_EDGES + 255) / 256, 256, 0, stream>>>(edge_index, coff, cur, csrc);
    k_wsplit<<<2048, 256, 0, stream>>>(conv_wl, conv_wr, WT);

    if (CH == 16) {
        k_x0<16><<<dim3(1250, 16), 256, 0, stream>>>(base, T, x_node_cfg, U, 0);
        for (int i = 0; i < 4; ++i) {
            k_agg<<<dim3(2500, 16), 256, 0, stream>>>(U, coff, csrc, invd);
            k_gemm<<<16 * N_NODES / 128, 512, 0, stream>>>(U, WT + i * 262144,
                                                           conv_bl + i * 256);
        }
        k_pool<16><<<dim3(40, 16), 256, 0, stream>>>(U, g, 0);
    } else {
        for (int cc = 0; cc < 2; ++cc) {
            k_x0<8><<<dim3(1250, 8), 256, 0, stream>>>(base, T, x_node_cfg, U, cc);
            for (int i = 0; i < 4; ++i) {
                k_agg<<<dim3(2500, 8), 256, 0, stream>>>(U, coff, csrc, invd);
                k_gemm<<<8 * N_NODES / 128, 512, 0, stream>>>(U, WT + i * 262144,
                                                              conv_bl + i * 256);
            }
            k_pool<8><<<dim3(40, 8), 256, 0, stream>>>(U, g, cc);
        }
    }

    k_head<<<16, 256, 0, stream>>>(g, w1, b1, w2, b2, w3, b3, out);
}

// Round 14
// 847.287 us; speedup vs baseline: 1.0660x; 1.0660x over previous
//
#include <hip/hip_runtime.h>

#define N_NODES 10000
#define N_CFG   16
#define N_EDGES 40000
#define UW      512               // U row: [agg 256 | x 256] (x updated in-place)

typedef __attribute__((ext_vector_type(8))) short bf16x8;
typedef __attribute__((ext_vector_type(4))) float floatx4;

__device__ __forceinline__ unsigned short f2bf(float f) {
    union { float f; unsigned int u; } v; v.f = f;
    unsigned int r = (v.u + 0x7fffu + ((v.u >> 16) & 1u)) >> 16;  // RNE
    return (unsigned short)r;
}
__device__ __forceinline__ float bf2f(unsigned short h) {
    union { unsigned int u; float f; } v; v.u = ((unsigned int)h) << 16;
    return v.f;
}
// acc[0..7] += 8 bf16 packed in uint4
__device__ __forceinline__ void add8(float* acc, uint4 v) {
    acc[0] += bf2f(v.x & 0xffff); acc[1] += bf2f(v.x >> 16);
    acc[2] += bf2f(v.y & 0xffff); acc[3] += bf2f(v.y >> 16);
    acc[4] += bf2f(v.z & 0xffff); acc[5] += bf2f(v.z >> 16);
    acc[6] += bf2f(v.w & 0xffff); acc[7] += bf2f(v.w >> 16);
}

// async global->LDS, 16B/lane; LDS dest MUST be wave-uniform + lane*16
__device__ __forceinline__ void gl_lds16(const unsigned short* g, unsigned short* l) {
    __builtin_amdgcn_global_load_lds(
        (const __attribute__((address_space(1))) unsigned int*)g,
        (__attribute__((address_space(3))) unsigned int*)l, 16, 0, 0);
}

// ---------------------------------------------------------------------------
// Feature build
// ---------------------------------------------------------------------------

__global__ __launch_bounds__(256) void k_table(const float* __restrict__ emb_layout,
                                               const float* __restrict__ lin_w,
                                               unsigned short* __restrict__ T) {
    int b = blockIdx.x;  // 0..143
    int j = b >> 3, v = b & 7;
    int d = threadIdx.x;
    float s = 0.f;
#pragma unroll
    for (int t = 0; t < 4; ++t)
        s = fmaf(emb_layout[v * 4 + t], lin_w[(140 + 4 * j + t) * 256 + d], s);
    T[b * 256 + d] = f2bf(s);
}

// 20 nodes per block: lin_w read once per block (k-outer loop)
__global__ __launch_bounds__(256) void k_base(const float* __restrict__ x_feat,
                                              const int* __restrict__ x_op,
                                              const float* __restrict__ emb_op,
                                              const float* __restrict__ lin_w,
                                              const float* __restrict__ lin_b,
                                              unsigned short* __restrict__ base) {
    __shared__ float xf[20][144];
    const int tid = threadIdx.x;
    const int n0 = blockIdx.x * 20;
    for (int j = tid; j < 20 * 140; j += 256)
        xf[j / 140][j % 140] = x_feat[(n0 + j / 140) * 140 + (j % 140)];
    if (tid < 80) {
        int i = tid >> 2, t = tid & 3;
        xf[i][140 + t] = emb_op[x_op[n0 + i] * 4 + t];
    }
    __syncthreads();
    const int d = tid;
    float acc[20];
#pragma unroll
    for (int i = 0; i < 20; ++i) acc[i] = 0.f;
    for (int k = 0; k < 140; ++k) {
        float w = lin_w[k * 256 + d];
#pragma unroll
        for (int i = 0; i < 20; ++i) acc[i] = fmaf(xf[i][k], w, acc[i]);
    }
#pragma unroll
    for (int t = 0; t < 4; ++t) {
        float w = lin_w[(212 + t) * 256 + d];
#pragma unroll
        for (int i = 0; i < 20; ++i) acc[i] = fmaf(xf[i][140 + t], w, acc[i]);
    }
    float bb = lin_b[d];
#pragma unroll
    for (int i = 0; i < 20; ++i)
        base[(n0 + i) * 256 + d] = f2bf(acc[i] + bb);
}

// x0 -> U x cols. Vectorized: 8 nodes/block, 32 threads/node, 8 cols/thread.
template <int CH>
__global__ __launch_bounds__(256) void k_x0(const unsigned short* __restrict__ base,
                                            const unsigned short* __restrict__ T,
                                            const int* __restrict__ cfg,
                                            unsigned short* __restrict__ U,
                                            int cc) {
    __shared__ int idx[8][18];
    const int tid = threadIdx.x;
    const int n0 = blockIdx.x * 8;
    const int cy = blockIdx.y;
    const int cg = cc * CH + cy;
    if (tid < 144) {
        int nl = tid / 18, j = tid % 18;
        idx[nl][j] = cfg[((size_t)cg * N_NODES + n0 + nl) * 18 + j];
    }
    __syncthreads();
    const int nl = tid >> 5;
    const int colg = (tid & 31) * 8;
    const int n = n0 + nl;
    float acc[8];
    uint4 bv = *(const uint4*)(base + n * 256 + colg);
    acc[0] = bf2f(bv.x & 0xffff); acc[1] = bf2f(bv.x >> 16);
    acc[2] = bf2f(bv.y & 0xffff); acc[3] = bf2f(bv.y >> 16);
    acc[4] = bf2f(bv.z & 0xffff); acc[5] = bf2f(bv.z >> 16);
    acc[6] = bf2f(bv.w & 0xffff); acc[7] = bf2f(bv.w >> 16);
#pragma unroll
    for (int j = 0; j < 18; ++j) {
        uint4 tv = *(const uint4*)(T + (j * 8 + idx[nl][j]) * 256 + colg);
        add8(acc, tv);
    }
    uint4 o;
    o.x = (unsigned int)f2bf(acc[0]) | ((unsigned int)f2bf(acc[1]) << 16);
    o.y = (unsigned int)f2bf(acc[2]) | ((unsigned int)f2bf(acc[3]) << 16);
    o.z = (unsigned int)f2bf(acc[4]) | ((unsigned int)f2bf(acc[5]) << 16);
    o.w = (unsigned int)f2bf(acc[6]) | ((unsigned int)f2bf(acc[7]) << 16);
    *(uint4*)(U + ((size_t)cy * N_NODES + n) * UW + 256 + colg) = o;
}

// ---------------------------------------------------------------------------
// CSR build
// ---------------------------------------------------------------------------

__global__ void k_deg(const int* __restrict__ ei, int* __restrict__ deg) {
    int e = blockIdx.x * 256 + threadIdx.x;
    if (e < N_EDGES) atomicAdd(&deg[ei[N_EDGES + e]], 1);
}

// prefix-scan over deg -> coff, plus invd = 1/max(deg,1) in the same pass
__global__ __launch_bounds__(256) void k_scan(const int* __restrict__ deg,
                                              int* __restrict__ coff,
                                              float* __restrict__ invd) {
    __shared__ int part[257];
    int t = threadIdx.x;
    const int CHk = 40;
    int start = t * CHk;
    int s = 0;
    for (int i = 0; i < CHk; ++i) {
        int idx = start + i;
        if (idx < N_NODES) s += deg[idx];
    }
    part[t + 1] = s;
    if (t == 0) part[0] = 0;
    __syncthreads();
    if (t == 0)
        for (int i = 1; i <= 256; ++i) part[i] += part[i - 1];
    __syncthreads();
    int run = part[t];
    for (int i = 0; i < CHk; ++i) {
        int idx = start + i;
        if (idx < N_NODES) {
            int d = deg[idx];
            coff[idx] = run; run += d;
            invd[idx] = 1.0f / fmaxf((float)d, 1.0f);
        }
    }
    if (t == 0) coff[N_NODES] = part[256];
}

__global__ void k_fill(const int* __restrict__ ei, const int* __restrict__ coff,
                       int* __restrict__ cur, int* __restrict__ csrc) {
    int e = blockIdx.x * 256 + threadIdx.x;
    if (e < N_EDGES) {
        int d = ei[N_EDGES + e];
        int s = ei[e];
        int pos = atomicAdd(&cur[d], 1);
        csrc[coff[d] + pos] = s;
    }
}

// WT[i][n][k]: k in [0,512) = bf16_hi(Wfused[k][n]); k in [512,1024) = bf16_lo
__global__ void k_wsplit(const float* __restrict__ wl, const float* __restrict__ wr,
                         unsigned short* __restrict__ WT) {
    int t = blockIdx.x * 256 + threadIdx.x;  // < 524288
    int i = t >> 17;
    int r = (t >> 8) & 511;
    int nn = t & 255;
    float w = (r < 256) ? wl[i * 65536 + r * 256 + nn]
                        : wr[i * 65536 + (r - 256) * 256 + nn];
    unsigned short hi = f2bf(w);
    unsigned short lo = f2bf(w - bf2f(hi));
    size_t b = (size_t)i * 262144 + (size_t)nn * 1024;
    WT[b + r] = hi;
    WT[b + 512 + r] = lo;
}

// ---------------------------------------------------------------------------
// Aggregation (r12 config — measured best; y=16 regressed, y=4 equal):
// one wave per node per 2-config group (grid.y = CH/2). 16B loads,
// half-wave edge parity, shfl_xor(32) merge.
// ---------------------------------------------------------------------------

__global__ __launch_bounds__(256) void k_agg(unsigned short* __restrict__ U,
                                             const int* __restrict__ coff,
                                             const int* __restrict__ csrc,
                                             const float* __restrict__ invd) {
    const int wave = threadIdx.x >> 6, lane = threadIdx.x & 63;
    const int n = blockIdx.x * 4 + wave;
    const size_t cbase = (size_t)blockIdx.y * 2 * N_NODES;
    const int e0 = coff[n], e1 = coff[n + 1];
    const int h = lane >> 5;          // edge parity
    const int cg = (lane & 31) * 8;   // col start
    float acc[2][8];
#pragma unroll
    for (int cy = 0; cy < 2; ++cy)
#pragma unroll
        for (int j = 0; j < 8; ++j) acc[cy][j] = 0.f;
    for (int e = e0 + h; e < e1; e += 2) {
        int s = csrc[e];
        const unsigned short* p = U + (cbase + s) * UW + 256 + cg;
        uint4 v0 = *(const uint4*)(p);
        uint4 v1 = *(const uint4*)(p + (size_t)N_NODES * UW);
        add8(acc[0], v0);
        add8(acc[1], v1);
    }
#pragma unroll
    for (int cy = 0; cy < 2; ++cy)
#pragma unroll
        for (int j = 0; j < 8; ++j)
            acc[cy][j] += __shfl_xor(acc[cy][j], 32, 64);
    if (h == 0) {
        float iv = invd[n];
#pragma unroll
        for (int cy = 0; cy < 2; ++cy) {
            uint4 o;
            o.x = (unsigned int)f2bf(acc[cy][0] * iv) |
                  ((unsigned int)f2bf(acc[cy][1] * iv) << 16);
            o.y = (unsigned int)f2bf(acc[cy][2] * iv) |
                  ((unsigned int)f2bf(acc[cy][3] * iv) << 16);
            o.z = (unsigned int)f2bf(acc[cy][4] * iv) |
                  ((unsigned int)f2bf(acc[cy][5] * iv) << 16);
            o.w = (unsigned int)f2bf(acc[cy][6] * iv) |
                  ((unsigned int)f2bf(acc[cy][7] * iv) << 16);
            *(uint4*)(U + (cbase + (size_t)cy * N_NODES + n) * UW + cg) = o;
        }
    }
}

// ---------------------------------------------------------------------------
// MFMA GEMM (r10/r12 config — measured best, 875 TF = m97-structure plateau):
// x = relu([agg|x]@(W_hi+W_lo)+b), in place. BM=128, BN=256 via 512 threads
// (8 waves, 64x64 quadrants; acc=64 VGPRs). global_load_lds staging; 40 KB
// LDS; XOR swizzle (0 conflicts r3-r13). Do not touch.
// ---------------------------------------------------------------------------

__global__ __launch_bounds__(512) void k_gemm(unsigned short* __restrict__ U,
                                              const unsigned short* __restrict__ WTl,
                                              const float* __restrict__ bias) {
    __shared__ unsigned short Asm[128 * 32];   // 8 KB
    __shared__ unsigned short Bh[256 * 32];    // 16 KB
    __shared__ unsigned short Bl[256 * 32];    // 16 KB
    const int tid = threadIdx.x;
    const int lane = tid & 63;
    const int wave = tid >> 6;                 // 0..7
    const int wm = wave >> 2;                  // row half (0/1)
    const int wn = wave & 3;                   // n-slice (64 wide)
    const size_t r0 = (size_t)blockIdx.x * 128;

    const int srow = tid >> 2;                     // staged row 0..127
    const int gc = (tid & 3) ^ ((srow >> 1) & 3);  // fetched k-granule (swizzle)

    const int colg = lane & 15, kg = lane >> 4, quad = lane >> 4;
    int aoff[4], boff[4];
#pragma unroll
    for (int t = 0; t < 4; ++t) {
        int ar = wm * 64 + t * 16 + colg;
        aoff[t] = ar * 32 + ((kg ^ ((ar >> 1) & 3)) << 3);
        int br = wn * 64 + t * 16 + colg;
        boff[t] = br * 32 + ((kg ^ ((br >> 1) & 3)) << 3);
    }

    floatx4 acc[4][4];
#pragma unroll
    for (int i = 0; i < 4; ++i)
#pragma unroll
        for (int j = 0; j < 4; ++j) acc[i][j] = (floatx4){0.f, 0.f, 0.f, 0.f};

    const unsigned short* Arow  = U + (r0 + srow) * UW + gc * 8;
    const unsigned short* Wrow0 = WTl + (size_t)srow * 1024 + gc * 8;          // n 0..127
    const unsigned short* Wrow1 = WTl + (size_t)(128 + srow) * 1024 + gc * 8;  // n 128..255

    for (int kt = 0; kt < 512; kt += 32) {
        gl_lds16(Arow + kt, Asm + tid * 8);
        gl_lds16(Wrow0 + kt,       Bh + tid * 8);
        gl_lds16(Wrow1 + kt,       Bh + 4096 + tid * 8);
        gl_lds16(Wrow0 + 512 + kt, Bl + tid * 8);
        gl_lds16(Wrow1 + 512 + kt, Bl + 4096 + tid * 8);
        __syncthreads();  // drains vmcnt -> staged data visible

        bf16x8 a[4], bh[4], bl[4];
#pragma unroll
        for (int t = 0; t < 4; ++t) a[t] = *(const bf16x8*)(Asm + aoff[t]);
#pragma unroll
        for (int t = 0; t < 4; ++t) {
            bh[t] = *(const bf16x8*)(Bh + boff[t]);
            bl[t] = *(const bf16x8*)(Bl + boff[t]);
        }
#pragma unroll
        for (int ti = 0; ti < 4; ++ti)
#pragma unroll
            for (int tj = 0; tj < 4; ++tj)
                acc[ti][tj] = __builtin_amdgcn_mfma_f32_16x16x32_bf16(
                    a[ti], bh[tj], acc[ti][tj], 0, 0, 0);
#pragma unroll
        for (int ti = 0; ti < 4; ++ti)
#pragma unroll
            for (int tj = 0; tj < 4; ++tj)
                acc[ti][tj] = __builtin_amdgcn_mfma_f32_16x16x32_bf16(
                    a[ti], bl[tj], acc[ti][tj], 0, 0, 0);
        __syncthreads();  // all waves done with LDS before restage
    }

#pragma unroll
    for (int tj = 0; tj < 4; ++tj) {
        int nn = wn * 64 + tj * 16 + colg;
        float bv = bias[nn];
#pragma unroll
        for (int ti = 0; ti < 4; ++ti) {
#pragma unroll
            for (int r = 0; r < 4; ++r) {
                size_t mm = r0 + (size_t)(wm * 64 + ti * 16 + quad * 4 + r);
                float y = acc[ti][tj][r] + bv;
                U[mm * UW + 256 + nn] = f2bf(fmaxf(y, 0.f));
            }
        }
    }
}

// ---------------------------------------------------------------------------
// Pool (vectorized: 8 row-groups x 32 lanes, uint4 reads, LDS reduce) + head
// ---------------------------------------------------------------------------

template <int CH>
__global__ __launch_bounds__(256) void k_pool(const unsigned short* __restrict__ U,
                                              float* __restrict__ g, int cc) {
    __shared__ float red[8][256];
    const int tid = threadIdx.x;
    const int grp = tid >> 5;          // row group 0..7
    const int cg = (tid & 31) * 8;     // col start
    const int cy = blockIdx.y;
    const size_t row0 = (size_t)cy * N_NODES + blockIdx.x * 250;
    float acc[8];
#pragma unroll
    for (int j = 0; j < 8; ++j) acc[j] = 0.f;
    for (int i = grp; i < 250; i += 8) {
        uint4 v = *(const uint4*)(U + (row0 + i) * UW + 256 + cg);
        add8(acc, v);
    }
#pragma unroll
    for (int j = 0; j < 8; ++j) red[grp][cg + j] = acc[j];
    __syncthreads();
    float s = 0.f;
#pragma unroll
    for (int k = 0; k < 8; ++k) s += red[k][tid];
    atomicAdd(&g[(cc * CH + cy) * 256 + tid], s);
}

__global__ __launch_bounds__(256) void k_head(const float* __restrict__ g,
                                              const float* __restrict__ w1,
                                              const float* __restrict__ b1,
                                              const float* __restrict__ w2,
                                              const float* __restrict__ b2,
                                              const float* __restrict__ w3,
                                              const float* __restrict__ b3,
                                              float* __restrict__ out) {
    __shared__ float ha[256];
    __shared__ float hb[256];
    __shared__ float red[4];
    int c = blockIdx.x;
    int d = threadIdx.x;
    ha[d] = g[c * 256 + d] / 10000.0f;
    __syncthreads();
    float s = b1[d];
#pragma unroll 4
    for (int k = 0; k < 256; ++k)
        s = fmaf(ha[k], w1[k * 256 + d], s);
    hb[d] = fmaxf(s, 0.f);
    __syncthreads();
    s = b2[d];
#pragma unroll 4
    for (int k = 0; k < 256; ++k)
        s = fmaf(hb[k], w2[k * 256 + d], s);
    ha[d] = fmaxf(s, 0.f);
    __syncthreads();
    float p = ha[d] * w3[d];
#pragma unroll
    for (int off = 32; off > 0; off >>= 1)
        p += __shfl_down(p, off, 64);
    if ((d & 63) == 0) red[d >> 6] = p;
    __syncthreads();
    if (d == 0)
        out[c] = red[0] + red[1] + red[2] + red[3] + b3[0];
}

__global__ void k_wsfail(float* __restrict__ out, float v) {
    out[threadIdx.x] = v;
}

// ---------------------------------------------------------------------------

extern "C" void kernel_launch(void* const* d_in, const int* in_sizes, int n_in,
                              void* d_out, int out_size, void* d_ws, size_t ws_size,
                              hipStream_t stream) {
    const int*   x_node_cfg = (const int*)  d_in[0];
    const float* x_feat     = (const float*)d_in[1];
    const int*   x_op       = (const int*)  d_in[2];
    const int*   edge_index = (const int*)  d_in[3];
    const float* emb_op     = (const float*)d_in[4];
    const float* emb_layout = (const float*)d_in[5];
    const float* lin_w      = (const float*)d_in[6];
    const float* lin_b      = (const float*)d_in[7];
    const float* conv_wl    = (const float*)d_in[8];
    const float* conv_bl    = (const float*)d_in[9];
    const float* conv_wr    = (const float*)d_in[10];
    const float* w1         = (const float*)d_in[11];
    const float* b1         = (const float*)d_in[12];
    const float* w2         = (const float*)d_in[13];
    const float* b2         = (const float*)d_in[14];
    const float* w3         = (const float*)d_in[15];
    const float* b3         = (const float*)d_in[16];
    float* out = (float*)d_out;

    // rest-of-workspace = 7,627,268 B; U = CH*10000*512*2 B
    const size_t NEED8  = (size_t)8  * N_NODES * UW * 2 + 7627268;  //  89.5 MB
    const size_t NEED16 = (size_t)16 * N_NODES * UW * 2 + 7627268;  // 171.5 MB
    const int CH = (ws_size >= NEED16) ? 16 : 8;

    unsigned short* U    = (unsigned short*)d_ws;          // [CH*10000][512]
    unsigned short* base = U + (size_t)CH * N_NODES * UW;  // [10000][256]
    unsigned short* T    = base + 2560000;                 // [18][8][256]
    unsigned short* WT   = T + 36864;                      // [4][256][1024]
    float* invd = (float*)(WT + 1048576);                  // [10000]
    float* g    = invd + 10000;                            // [16][256] pad 4096
    int* deg  = (int*)(g + 4096);                          // [10000]
    int* coff = deg + 10000;                               // [10001]
    int* cur  = coff + 10001;                              // [10000]
    int* csrc = cur + 10000;                               // [40000]

    if (ws_size < NEED8) {
        k_wsfail<<<1, 16, 0, stream>>>(out, (float)ws_size * 1e-9f);
        return;
    }

    // g, deg, coff, cur are contiguous -> one clear (coff is overwritten anyway)
    hipMemsetAsync(g, 0, (size_t)(4096 + 10000 + 10001 + 10000) * 4, stream);

    k_table<<<144, 256, 0, stream>>>(emb_layout, lin_w, T);
    k_base<<<500, 256, 0, stream>>>(x_feat, x_op, emb_op, lin_w, lin_b, base);
    k_deg<<<(N_EDGES + 255) / 256, 256, 0, stream>>>(edge_index, deg);
    k_scan<<<1, 256, 0, stream>>>(deg, coff, invd);
    k_fill<<<(N_EDGES + 255) / 256, 256, 0, stream>>>(edge_index, coff, cur, csrc);
    k_wsplit<<<2048, 256, 0, stream>>>(conv_wl, conv_wr, WT);

    if (CH == 16) {
        k_x0<16><<<dim3(1250, 16), 256, 0, stream>>>(base, T, x_node_cfg, U, 0);
        for (int i = 0; i < 4; ++i) {
            k_agg<<<dim3(2500, 8), 256, 0, stream>>>(U, coff, csrc, invd);
            k_gemm<<<16 * N_NODES / 128, 512, 0, stream>>>(U, WT + i * 262144,
                                                           conv_bl + i * 256);
        }
        k_pool<16><<<dim3(40, 16), 256, 0, stream>>>(U, g, 0);
    } else {
        for (int cc = 0; cc < 2; ++cc) {
            k_x0<8><<<dim3(1250, 8), 256, 0, stream>>>(base, T, x_node_cfg, U, cc);
            for (int i = 0; i < 4; ++i) {
                k_agg<<<dim3(2500, 4), 256, 0, stream>>>(U, coff, csrc, invd);
                k_gemm<<<8 * N_NODES / 128, 512, 0, stream>>>(U, WT + i * 262144,
                                                              conv_bl + i * 256);
            }
            k_pool<8><<<dim3(40, 8), 256, 0, stream>>>(U, g, cc);
        }
    }

    k_head<<<16, 256, 0, stream>>>(g, w1, b1, w2, b2, w3, b3, out);
}